// Round 4
// baseline (37.663 us; speedup 1.0000x reference)
//
#include <hip/hip_runtime.h>
#include <hip/hip_bf16.h>

// out[b, e] = relu(cos(qp[0]+qp[1])) * (W2[e,0]+W2[e,1]+W2[e,2]+W2[e,3]) + b2[e]
// Every batch row is identical -> compute 4 e-values per thread, broadcast-store.
// B=8192, E=2048, FF=8192. Pure store-BW-bound: 64 MiB of f32 stores.
//
// DIAGNOSTIC ROUND: launch the identical kernel TWICE (idempotent stores).
// Marginal wall-time = true per-dispatch cost, separating kernel time from
// fixed graph-replay overhead.

typedef float v4f __attribute__((ext_vector_type(4)));

__global__ __launch_bounds__(256) void qffn_broadcast_kernel(
    const float* __restrict__ W2,   // (E, FF) row-major
    const float* __restrict__ b2,   // (E,)
    const float* __restrict__ qp,   // (NQ, DEPTH) flat; need qp[0], qp[1]
    float* __restrict__ out,        // (B, E) row-major
    int E, int FF, int B, int rows_per_block)
{
    const int c  = blockIdx.x * blockDim.x + threadIdx.x;   // [0, E/4)
    const int e0 = c * 4;

    const v4f w0 = *reinterpret_cast<const v4f*>(W2 + (size_t)(e0 + 0) * FF);
    const v4f w1 = *reinterpret_cast<const v4f*>(W2 + (size_t)(e0 + 1) * FF);
    const v4f w2 = *reinterpret_cast<const v4f*>(W2 + (size_t)(e0 + 2) * FF);
    const v4f w3 = *reinterpret_cast<const v4f*>(W2 + (size_t)(e0 + 3) * FF);
    const v4f bb = *reinterpret_cast<const v4f*>(b2 + e0);
    const float q0 = qp[0];
    const float q1 = qp[1];

    float qv = fmaxf(cosf(q0 + q1), 0.0f);

    v4f r;
    r.x = qv * (w0.x + w0.y + w0.z + w0.w) + bb.x;
    r.y = qv * (w1.x + w1.y + w1.z + w1.w) + bb.y;
    r.z = qv * (w2.x + w2.y + w2.z + w2.w) + bb.z;
    r.w = qv * (w3.x + w3.y + w3.z + w3.w) + bb.w;

    const size_t row_stride = (size_t)(E / 4);
    v4f* base =
        reinterpret_cast<v4f*>(out) + (size_t)blockIdx.y * rows_per_block * row_stride + c;

    #pragma unroll
    for (int i = 0; i < 8; ++i) {   // rows_per_block == 8
        __builtin_nontemporal_store(r, base + (size_t)i * row_stride);
    }
}

extern "C" void kernel_launch(void* const* d_in, const int* in_sizes, int n_in,
                              void* d_out, int out_size, void* d_ws, size_t ws_size,
                              hipStream_t stream)
{
    // inputs (setup_inputs order): x, W1, b1, W2, b2, q_params
    const float* W2 = (const float*)d_in[3];
    const float* b2 = (const float*)d_in[4];
    const float* qp = (const float*)d_in[5];
    float* out = (float*)d_out;

    const int E  = in_sizes[4];            // 2048
    const int FF = in_sizes[2];            // 8192
    const int B  = out_size / E;           // 8192

    const int threads = 256;
    const int rows_per_block = 8;
    dim3 grid(E / 4 / threads, B / rows_per_block);  // (2, 1024)
    dim3 block(threads);

    // Dispatch TWICE — idempotent; second dispatch's marginal wall-time
    // reveals the true kernel duration vs fixed replay overhead.
    qffn_broadcast_kernel<<<grid, block, 0, stream>>>(W2, b2, qp, out, E, FF, B, rows_per_block);
    qffn_broadcast_kernel<<<grid, block, 0, stream>>>(W2, b2, qp, out, E, FF, B, rows_per_block);
}

// Round 5
// 22.684 us; speedup vs baseline: 1.6603x; 1.6603x over previous
//
#include <hip/hip_runtime.h>
#include <hip/hip_bf16.h>

// out[b, e] = relu(cos(qp[0]+qp[1])) * (W2[e,0]+W2[e,1]+W2[e,2]+W2[e,3]) + b2[e]
// Every batch row is identical. B=8192, E=2048, FF=8192.
// Store-BW-bound: 64 MiB f32. Strategy: flat contiguous grid-stride sweep
// (same pattern as rocclr fillBuffer, which hits 6.7 TB/s on this chip).

typedef float v4f __attribute__((ext_vector_type(4)));

__global__ __launch_bounds__(256) void qffn_flat_kernel(
    const float* __restrict__ W2,   // (E, FF) row-major
    const float* __restrict__ b2,   // (E,)
    const float* __restrict__ qp,   // flat; need qp[0], qp[1]
    float* __restrict__ out,        // (B, E) row-major, viewed as flat float4
    int E, int FF, size_t total4)   // total4 = B*E/4
{
    const size_t tid = (size_t)blockIdx.x * blockDim.x + threadIdx.x;
    // grid stride (524288) is a multiple of E/4 (512) -> column is loop-invariant
    const int c  = (int)(tid & (size_t)(E / 4 - 1));   // float4 column in row
    const int e0 = c * 4;

    const v4f w0 = *reinterpret_cast<const v4f*>(W2 + (size_t)(e0 + 0) * FF);
    const v4f w1 = *reinterpret_cast<const v4f*>(W2 + (size_t)(e0 + 1) * FF);
    const v4f w2 = *reinterpret_cast<const v4f*>(W2 + (size_t)(e0 + 2) * FF);
    const v4f w3 = *reinterpret_cast<const v4f*>(W2 + (size_t)(e0 + 3) * FF);
    const v4f bb = *reinterpret_cast<const v4f*>(b2 + e0);
    const float q0 = qp[0];
    const float q1 = qp[1];

    const float qv = fmaxf(cosf(q0 + q1), 0.0f);

    v4f r;
    r.x = qv * (w0.x + w0.y + w0.z + w0.w) + bb.x;
    r.y = qv * (w1.x + w1.y + w1.z + w1.w) + bb.y;
    r.z = qv * (w2.x + w2.y + w2.z + w2.w) + bb.z;
    r.w = qv * (w3.x + w3.y + w3.z + w3.w) + bb.w;

    v4f* __restrict__ o = reinterpret_cast<v4f*>(out);
    const size_t stride = (size_t)gridDim.x * blockDim.x;

    #pragma unroll
    for (int k = 0; k < 8; ++k) {           // 4M / 524288 = 8 iterations
        size_t p = tid + (size_t)k * stride;
        if (p < total4) o[p] = r;
    }
}

extern "C" void kernel_launch(void* const* d_in, const int* in_sizes, int n_in,
                              void* d_out, int out_size, void* d_ws, size_t ws_size,
                              hipStream_t stream)
{
    // inputs (setup_inputs order): x, W1, b1, W2, b2, q_params
    const float* W2 = (const float*)d_in[3];
    const float* b2 = (const float*)d_in[4];
    const float* qp = (const float*)d_in[5];
    float* out = (float*)d_out;

    const int E  = in_sizes[4];            // 2048
    const int FF = in_sizes[2];            // 8192
    const size_t total4 = (size_t)out_size / 4;   // B*E/4 = 4,194,304

    const int threads = 256;
    const int blocks  = 2048;              // 8 blocks/CU; stride covers total in 8 sweeps

    qffn_flat_kernel<<<dim3(blocks), dim3(threads), 0, stream>>>(
        W2, b2, qp, out, E, FF, total4);
}

// Round 6
// 18.056 us; speedup vs baseline: 2.0859x; 1.2563x over previous
//
#include <hip/hip_runtime.h>
#include <hip/hip_bf16.h>

// out[b, e] = relu(cos(qp[0]+qp[1])) * (W2[e,0..3].sum()) + b2[e]
// Every batch row identical. B=8192, E=2048, FF=8192. 64 MiB f32 stores.
//
// R6: the limiter was L2 read-transaction pressure from the per-block
// scattered W2 gather (4 instrs/wave x 64 lanes x 32KB stride), replicated
// across 2048 blocks (~2.6M L2 transactions vs 1.05M for all stores).
// Fix: 512 blocks only, each thread computes r once and stores 32 float4s.
// Gather transactions drop 5x; stores still saturate (8 waves/CU, 32
// outstanding stores per wave).

typedef float v4f __attribute__((ext_vector_type(4)));

__global__ __launch_bounds__(256) void qffn_deep_kernel(
    const float* __restrict__ W2,   // (E, FF) row-major
    const float* __restrict__ b2,   // (E,)
    const float* __restrict__ qp,   // flat; need qp[0], qp[1]
    float* __restrict__ out,        // (B, E) row-major, viewed as flat float4
    int E, int FF, size_t total4)   // total4 = B*E/4 = 4,194,304
{
    const size_t tid = (size_t)blockIdx.x * blockDim.x + threadIdx.x;  // [0, 131072)
    // stride (131072) is a multiple of E/4 (512) -> column is loop-invariant
    const int c  = (int)(tid & (size_t)(E / 4 - 1));   // float4 column in row
    const int e0 = c * 4;

    const v4f w0 = *reinterpret_cast<const v4f*>(W2 + (size_t)(e0 + 0) * FF);
    const v4f w1 = *reinterpret_cast<const v4f*>(W2 + (size_t)(e0 + 1) * FF);
    const v4f w2 = *reinterpret_cast<const v4f*>(W2 + (size_t)(e0 + 2) * FF);
    const v4f w3 = *reinterpret_cast<const v4f*>(W2 + (size_t)(e0 + 3) * FF);
    const v4f bb = *reinterpret_cast<const v4f*>(b2 + e0);
    const float q0 = qp[0];
    const float q1 = qp[1];

    const float qv = fmaxf(cosf(q0 + q1), 0.0f);

    v4f r;
    r.x = qv * (w0.x + w0.y + w0.z + w0.w) + bb.x;
    r.y = qv * (w1.x + w1.y + w1.z + w1.w) + bb.y;
    r.z = qv * (w2.x + w2.y + w2.z + w2.w) + bb.z;
    r.w = qv * (w3.x + w3.y + w3.z + w3.w) + bb.w;

    v4f* __restrict__ o = reinterpret_cast<v4f*>(out);
    const size_t stride = (size_t)gridDim.x * blockDim.x;   // 131072

    #pragma unroll
    for (int k = 0; k < 32; ++k) {          // 4M / 131072 = 32 iterations
        size_t p = tid + (size_t)k * stride;
        o[p] = r;                            // exact cover: 32*131072 == total4
    }
}

extern "C" void kernel_launch(void* const* d_in, const int* in_sizes, int n_in,
                              void* d_out, int out_size, void* d_ws, size_t ws_size,
                              hipStream_t stream)
{
    // inputs (setup_inputs order): x, W1, b1, W2, b2, q_params
    const float* W2 = (const float*)d_in[3];
    const float* b2 = (const float*)d_in[4];
    const float* qp = (const float*)d_in[5];
    float* out = (float*)d_out;

    const int E  = in_sizes[4];            // 2048
    const int FF = in_sizes[2];            // 8192
    const size_t total4 = (size_t)out_size / 4;   // 4,194,304

    const int threads = 256;
    const int blocks  = 512;               // 2 blocks/CU; 32 stores/thread

    qffn_deep_kernel<<<dim3(blocks), dim3(threads), 0, stream>>>(
        W2, b2, qp, out, E, FF, total4);
}

// Round 9
// 17.800 us; speedup vs baseline: 2.1159x; 1.0144x over previous
//
#include <hip/hip_runtime.h>
#include <hip/hip_bf16.h>

// out[b, e] = relu(cos(qp[0]+qp[1])) * (W2[e,0..3].sum()) + b2[e]
// Every batch row identical. B=8192, E=2048, FF=8192. 64 MiB f32 stores.
//
// R7 (2nd rerun after infra failures): gather transactions scale with total
// threads (4 scattered float4 loads/thread, irreducible). R5->R6
// (524K->131K threads) saved ~4us. Halve again: 65536 threads
// (256 blocks x 256 = 1 block/CU), 64 stores/thread. Stores are
// fire-and-forget so 4 waves/CU suffices for issue.

typedef float v4f __attribute__((ext_vector_type(4)));

__global__ __launch_bounds__(256) void qffn_deep_kernel(
    const float* __restrict__ W2,   // (E, FF) row-major
    const float* __restrict__ b2,   // (E,)
    const float* __restrict__ qp,   // flat; need qp[0], qp[1]
    float* __restrict__ out,        // (B, E) row-major, viewed as flat float4
    int E, int FF, size_t total4)   // total4 = B*E/4 = 4,194,304
{
    const size_t tid = (size_t)blockIdx.x * blockDim.x + threadIdx.x;  // [0, 65536)
    // stride (65536) is a multiple of E/4 (512) -> column is loop-invariant
    const int c  = (int)(tid & (size_t)(E / 4 - 1));   // float4 column in row
    const int e0 = c * 4;

    const v4f w0 = *reinterpret_cast<const v4f*>(W2 + (size_t)(e0 + 0) * FF);
    const v4f w1 = *reinterpret_cast<const v4f*>(W2 + (size_t)(e0 + 1) * FF);
    const v4f w2 = *reinterpret_cast<const v4f*>(W2 + (size_t)(e0 + 2) * FF);
    const v4f w3 = *reinterpret_cast<const v4f*>(W2 + (size_t)(e0 + 3) * FF);
    const v4f bb = *reinterpret_cast<const v4f*>(b2 + e0);
    const float q0 = qp[0];
    const float q1 = qp[1];

    const float qv = fmaxf(cosf(q0 + q1), 0.0f);

    v4f r;
    r.x = qv * (w0.x + w0.y + w0.z + w0.w) + bb.x;
    r.y = qv * (w1.x + w1.y + w1.z + w1.w) + bb.y;
    r.z = qv * (w2.x + w2.y + w2.z + w2.w) + bb.z;
    r.w = qv * (w3.x + w3.y + w3.z + w3.w) + bb.w;

    v4f* __restrict__ o = reinterpret_cast<v4f*>(out);
    const size_t stride = (size_t)gridDim.x * blockDim.x;   // 65536

    #pragma unroll
    for (int k = 0; k < 64; ++k) {          // 4M / 65536 = 64 iterations
        size_t p = tid + (size_t)k * stride;
        o[p] = r;                            // exact cover: 64*65536 == total4
    }
}

extern "C" void kernel_launch(void* const* d_in, const int* in_sizes, int n_in,
                              void* d_out, int out_size, void* d_ws, size_t ws_size,
                              hipStream_t stream)
{
    // inputs (setup_inputs order): x, W1, b1, W2, b2, q_params
    const float* W2 = (const float*)d_in[3];
    const float* b2 = (const float*)d_in[4];
    const float* qp = (const float*)d_in[5];
    float* out = (float*)d_out;

    const int E  = in_sizes[4];            // 2048
    const int FF = in_sizes[2];            // 8192
    const size_t total4 = (size_t)out_size / 4;   // 4,194,304

    const int threads = 256;
    const int blocks  = 256;               // 1 block/CU; 64 stores/thread

    qffn_deep_kernel<<<dim3(blocks), dim3(threads), 0, stream>>>(
        W2, b2, qp, out, E, FF, total4);
}